// Round 2
// 346.886 us; speedup vs baseline: 1.7036x; 1.7036x over previous
//
#include <hip/hip_runtime.h>
#include <hip/hip_bf16.h>

typedef __hip_bfloat16 bf16;

#define HW 4096

typedef short s4v __attribute__((ext_vector_type(4)));
typedef float f32x4 __attribute__((ext_vector_type(4)));
typedef _Float16 h8v __attribute__((ext_vector_type(8)));
typedef _Float16 h4v __attribute__((ext_vector_type(4)));

__device__ __forceinline__ float b2f(bf16 x) { return __bfloat162float(x); }
__device__ __forceinline__ bf16 f2b(float x) { return __float2bfloat16(x); }

__device__ __forceinline__ unsigned short f2bs(float f) {
  bf16 h = __float2bfloat16(f);
  unsigned short s;
  __builtin_memcpy(&s, &h, 2);
  return s;
}
__device__ __forceinline__ float s2f(short s) {
  return __uint_as_float(((unsigned)(unsigned short)s) << 16);
}
__device__ __forceinline__ short h2s(_Float16 h) {
  short s;
  __builtin_memcpy(&s, &h, 2);
  return s;
}

__device__ __forceinline__ void stv(float* p, float v) { *p = v; }
__device__ __forceinline__ void stv(bf16* p, float v) { *p = f2b(v); }

// ---------------------------------------------------------------------------
// fp32 -> (fp16 hi, fp16 lo) split conversion for weights.
// hi = rn(w); lo = rn(w - hi)  =>  hi + lo == w to ~2^-22 rel.
// ---------------------------------------------------------------------------
__global__ __launch_bounds__(256) void cvt_split_kernel(
    const float* __restrict__ W, _Float16* __restrict__ Hi,
    _Float16* __restrict__ Lo, int n4) {
  int i = blockIdx.x * 256 + threadIdx.x;
  if (i >= n4) return;
  f32x4 v = *(const f32x4*)(W + (size_t)i * 4);
  h4v h, l;
#pragma unroll
  for (int q = 0; q < 4; ++q) {
    _Float16 hi = (_Float16)v[q];
    h[q] = hi;
    l[q] = (_Float16)(v[q] - (float)hi);
  }
  *(h4v*)(Hi + (size_t)i * 4) = h;
  *(h4v*)(Lo + (size_t)i * 4) = l;
}

// ---------------------------------------------------------------------------
// Transpose + split: x [b][256][HW] f32 -> hi/lo [b][HW][256] f16.
// ---------------------------------------------------------------------------
__global__ __launch_bounds__(256) void transpose_split_kernel(
    const float* __restrict__ In, _Float16* __restrict__ Hi,
    _Float16* __restrict__ Lo) {
  __shared__ _Float16 sH[64][68];
  __shared__ _Float16 sL[64][68];
  const int b = blockIdx.z;
  const int n0 = blockIdx.x * 64, c0 = blockIdx.y * 64;
  const int tl = threadIdx.x & 15, tr = threadIdx.x >> 4;
  const float* Ib = In + ((size_t)b * 256 + c0) * HW + n0;
#pragma unroll
  for (int i = 0; i < 4; ++i) {
    int cc = tr + i * 16;
    f32x4 v = *(const f32x4*)(Ib + (size_t)cc * HW + tl * 4);
#pragma unroll
    for (int q = 0; q < 4; ++q) {
      _Float16 hi = (_Float16)v[q];
      sH[cc][tl * 4 + q] = hi;
      sL[cc][tl * 4 + q] = (_Float16)(v[q] - (float)hi);
    }
  }
  __syncthreads();
  size_t obase = ((size_t)b * HW + n0) * 256 + c0;
#pragma unroll
  for (int i = 0; i < 4; ++i) {
    int nn = tr + i * 16;
    h4v h, l;
#pragma unroll
    for (int q = 0; q < 4; ++q) {
      h[q] = sH[tl * 4 + q][nn];
      l[q] = sL[tl * 4 + q][nn];
    }
    *(h4v*)(Hi + obase + (size_t)nn * 256 + tl * 4) = h;
    *(h4v*)(Lo + obase + (size_t)nn * 256 + tl * 4) = l;
  }
}

// ---------------------------------------------------------------------------
// Transpose att [b][512][HW] bf16 -> att_t [b][HW][512] f16 (exact convert).
// ---------------------------------------------------------------------------
__global__ __launch_bounds__(256) void transpose_b2h_kernel(
    const bf16* __restrict__ In, _Float16* __restrict__ Outp) {
  __shared__ short sT[64][68];
  const int b = blockIdx.z;
  const int n0 = blockIdx.x * 64, c0 = blockIdx.y * 64;
  const int tl = threadIdx.x & 15, tr = threadIdx.x >> 4;
  const bf16* Ib = In + ((size_t)b * 512 + c0) * HW + n0;
#pragma unroll
  for (int i = 0; i < 4; ++i) {
    int cc = tr + i * 16;
    s4v v = *(const s4v*)(Ib + (size_t)cc * HW + tl * 4);
#pragma unroll
    for (int q = 0; q < 4; ++q) sT[cc][tl * 4 + q] = h2s((_Float16)s2f(v[q]));
  }
  __syncthreads();
  short* Ob = (short*)Outp + ((size_t)b * HW + n0) * 512 + c0;
#pragma unroll
  for (int i = 0; i < 4; ++i) {
    int nn = tr + i * 16;
    s4v r;
#pragma unroll
    for (int q = 0; q < 4; ++q) r[q] = sT[tl * 4 + q][nn];
    *(s4v*)(Ob + (size_t)nn * 512 + tl * 4) = r;
  }
}

// ---------------------------------------------------------------------------
// fp16 MFMA GEMM with split-precision planes.
// Out[b][o][n] = sum_k (sum_p A_p[o][k]) * (sum_q B_q[b][n][k]),
// computed as A0*B0 + A1*B0 + A0*B1 (lo*lo dropped, ~2^-22).
// Tile BM(m) x 128(n) x 32(k), 256 thr = 4 waves (2x2), 16x16x32 f16 MFMA.
// Staging: global h8v -> ds_write_b128 into padded linear LDS (LDR=40 el
// = 80 B row stride -> 2-way bank aliasing on ds_read_b128, free per m136).
// ---------------------------------------------------------------------------
template <int M, int K, int BM, int AP, int BP, bool FUSE_BN, typename TOUT>
__global__ __launch_bounds__(256) void mfma_gemm_f16(
    const _Float16* __restrict__ A,   // [AP][M][K] planes
    const _Float16* __restrict__ Bt,  // [BP][8][HW][K] planes
    TOUT* __restrict__ Out,           // [8][M][HW]
    const float* __restrict__ bng, const float* __restrict__ bnb,
    const float* __restrict__ bnm, const float* __restrict__ bnv) {
  constexpr int WMF = BM / 32;  // 16-row m-fragments per wave
  constexpr int LDR = 40;       // padded LDS row stride (elements)
  __shared__ _Float16 sA[AP][BM * LDR];
  __shared__ _Float16 sB[BP][128 * LDR];
  const int b = blockIdx.z;
  const int ob = blockIdx.y * BM;
  const int nb = blockIdx.x * 128;
  const int tid = threadIdx.x;
  const int lane = tid & 63;
  const int wave = tid >> 6;
  const int wm = (wave >> 1) * (BM / 2);
  const int wn = (wave & 1) * 64;
  const int lr = lane & 15;
  const int kg = lane >> 4;

  f32x4 acc[WMF][4] = {};

  for (int k0 = 0; k0 < K; k0 += 32) {
    // ---- stage A planes: BM rows x 32 k, 16B chunks, row-major padded ----
#pragma unroll
    for (int p = 0; p < AP; ++p) {
      const _Float16* Ab = A + (size_t)p * M * K + (size_t)ob * K;
#pragma unroll
      for (int t = 0; t < BM / 64; ++t) {
        int c = t * 256 + tid;
        int row = c >> 2, col = c & 3;
        h8v v = *(const h8v*)(Ab + (size_t)row * K + k0 + col * 8);
        *(h8v*)(&sA[p][row * LDR + col * 8]) = v;
      }
    }
    // ---- stage B planes: 128 rows x 32 k ----
#pragma unroll
    for (int q = 0; q < BP; ++q) {
      const _Float16* Bb =
          Bt + (size_t)q * 8 * HW * K + ((size_t)b * HW + nb) * K;
#pragma unroll
      for (int t = 0; t < 2; ++t) {
        int c = t * 256 + tid;
        int row = c >> 2, col = c & 3;
        h8v v = *(const h8v*)(Bb + (size_t)row * K + k0 + col * 8);
        *(h8v*)(&sB[q][row * LDR + col * 8]) = v;
      }
    }
    __syncthreads();

    h8v af[AP][WMF], bf_[BP][4];
#pragma unroll
    for (int p = 0; p < AP; ++p)
#pragma unroll
      for (int i = 0; i < WMF; ++i)
        af[p][i] = *(const h8v*)(&sA[p][(wm + i * 16 + lr) * LDR + kg * 8]);
#pragma unroll
    for (int q = 0; q < BP; ++q)
#pragma unroll
      for (int j = 0; j < 4; ++j)
        bf_[q][j] = *(const h8v*)(&sB[q][(wn + j * 16 + lr) * LDR + kg * 8]);

#pragma unroll
    for (int i = 0; i < WMF; ++i)
#pragma unroll
      for (int j = 0; j < 4; ++j) {
        acc[i][j] = __builtin_amdgcn_mfma_f32_16x16x32_f16(af[0][i], bf_[0][j],
                                                           acc[i][j], 0, 0, 0);
        if (AP > 1)
          acc[i][j] = __builtin_amdgcn_mfma_f32_16x16x32_f16(
              af[1][i], bf_[0][j], acc[i][j], 0, 0, 0);
        if (BP > 1)
          acc[i][j] = __builtin_amdgcn_mfma_f32_16x16x32_f16(
              af[0][i], bf_[1][j], acc[i][j], 0, 0, 0);
      }
    __syncthreads();
  }

  // epilogue: D row = (lane>>4)*4 + reg, col = lane&15  (m89-verified)
#pragma unroll
  for (int i = 0; i < WMF; ++i) {
#pragma unroll
    for (int r = 0; r < 4; ++r) {
      int o = ob + wm + i * 16 + kg * 4 + r;
      float scale = 1.f, shift = 0.f;
      if (FUSE_BN) {
        scale = bng[o] * rsqrtf(bnv[o] + 1e-5f);
        shift = bnb[o] - bnm[o] * scale;
      }
      TOUT* orow = Out + ((size_t)b * M + o) * HW + nb + wn + lr;
#pragma unroll
      for (int j = 0; j < 4; ++j) {
        float v = acc[i][j][r];
        if (FUSE_BN) v = v * scale + shift;
        stv(orow + j * 16, v);
      }
    }
  }
}

// ---------------------------------------------------------------------------
// Fused depthwise 5x5 conv + grouped pointwise (8->8 per group). (unchanged)
// ---------------------------------------------------------------------------
__global__ __launch_bounds__(256) void dwpw_kernel(
    const bf16* __restrict__ qkv,   // [B, 768, HW]
    const float* __restrict__ wdw,  // [768, 25]
    const float* __restrict__ wpw,  // [96, 8, 8]
    bf16* __restrict__ pw) {        // [B, 768, HW]
  __shared__ float sT[8][12][68];
  __shared__ float sWd[8][25];
  __shared__ float sWp[8][8];
  const int b = blockIdx.z;
  const int g = blockIdx.y;
  const int h0 = blockIdx.x * 8;
  const int tid = threadIdx.x;
  for (int i = tid; i < 200; i += 256)
    sWd[i / 25][i % 25] = wdw[(g * 8 + i / 25) * 25 + i % 25];
  if (tid < 64) sWp[tid >> 3][tid & 7] = wpw[g * 64 + tid];
  const bf16* qb = qkv + ((size_t)b * 768 + g * 8) * HW;
  for (int idx = tid; idx < 8 * 12 * 68; idx += 256) {
    int ci = idx / (12 * 68);
    int rem = idx % (12 * 68);
    int rr = rem / 68, cc = rem % 68;
    int h = h0 + rr - 2, w = cc - 2;
    float v = 0.f;
    if (h >= 0 && h < 64 && w >= 0 && w < 64) v = b2f(qb[(size_t)ci * HW + h * 64 + w]);
    sT[ci][rr][cc] = v;
  }
  __syncthreads();
  const int tw = tid & 63, th = tid >> 6;
#pragma unroll
  for (int rep = 0; rep < 2; ++rep) {
    int rl = th + rep * 4;
    float dwv[8];
#pragma unroll
    for (int ci = 0; ci < 8; ++ci) {
      float a = 0.f;
#pragma unroll
      for (int dy = 0; dy < 5; ++dy)
#pragma unroll
        for (int dx = 0; dx < 5; ++dx)
          a = fmaf(sT[ci][rl + dy][tw + dx], sWd[ci][dy * 5 + dx], a);
      dwv[ci] = a;
    }
    bf16* ob = pw + ((size_t)b * 768 + g * 8) * HW + (h0 + rl) * 64 + tw;
#pragma unroll
    for (int o = 0; o < 8; ++o) {
      float a = 0.f;
#pragma unroll
      for (int i = 0; i < 8; ++i) a = fmaf(sWp[o][i], dwv[i], a);
      ob[(size_t)o * HW] = f2b(a);
    }
  }
}

// ---------------------------------------------------------------------------
// ReLU linear attention, short4-vectorized loads/stores (4 px / thread).
// ---------------------------------------------------------------------------
__global__ __launch_bounds__(256) void attn_kernel(
    const bf16* __restrict__ qkv,  // [B, 768, HW]
    const bf16* __restrict__ pw,   // [B, 768, HW]
    bf16* __restrict__ att) {      // [B, 512, HW]
  const int bh = blockIdx.x;
  const int b = bh >> 6, h = bh & 63;
  const bf16* src = (h < 32) ? qkv + ((size_t)b * 768 + 24 * h) * HW
                             : pw + ((size_t)b * 768 + 24 * h - 768) * HW;
  const int tid = threadIdx.x;
  float kv[72] = {};  // kv[d*9+e]
  for (int n0 = tid * 4; n0 < HW; n0 += 1024) {
    s4v kvec[8], vvec[8];
#pragma unroll
    for (int d = 0; d < 8; ++d)
      kvec[d] = *(const s4v*)(src + (size_t)(8 + d) * HW + n0);
#pragma unroll
    for (int e = 0; e < 8; ++e)
      vvec[e] = *(const s4v*)(src + (size_t)(16 + e) * HW + n0);
#pragma unroll
    for (int p = 0; p < 4; ++p) {
      float kd[8], ve[8];
#pragma unroll
      for (int d = 0; d < 8; ++d) kd[d] = fmaxf(s2f(kvec[d][p]), 0.f);
#pragma unroll
      for (int e = 0; e < 8; ++e) ve[e] = s2f(vvec[e][p]);
#pragma unroll
      for (int d = 0; d < 8; ++d) {
#pragma unroll
        for (int e = 0; e < 8; ++e) kv[d * 9 + e] = fmaf(kd[d], ve[e], kv[d * 9 + e]);
        kv[d * 9 + 8] += kd[d];
      }
    }
  }
  __shared__ float sRed[4][72];
  __shared__ float sKV[72];
  const int lane = tid & 63, wave = tid >> 6;
#pragma unroll
  for (int t = 0; t < 72; ++t) {
    float v = kv[t];
    v += __shfl_down(v, 32);
    v += __shfl_down(v, 16);
    v += __shfl_down(v, 8);
    v += __shfl_down(v, 4);
    v += __shfl_down(v, 2);
    v += __shfl_down(v, 1);
    if (lane == 0) sRed[wave][t] = v;
  }
  __syncthreads();
  if (tid < 72) sKV[tid] = sRed[0][tid] + sRed[1][tid] + sRed[2][tid] + sRed[3][tid];
  __syncthreads();
  float kvf[72];
#pragma unroll
  for (int t = 0; t < 72; ++t) kvf[t] = sKV[t];
  bf16* obase = att + ((size_t)b * 512 + h * 8) * HW;
  for (int n0 = tid * 4; n0 < HW; n0 += 1024) {
    s4v qvec[8];
#pragma unroll
    for (int d = 0; d < 8; ++d)
      qvec[d] = *(const s4v*)(src + (size_t)d * HW + n0);
    s4v res[8];
#pragma unroll
    for (int p = 0; p < 4; ++p) {
      float qd[8];
#pragma unroll
      for (int d = 0; d < 8; ++d) qd[d] = fmaxf(s2f(qvec[d][p]), 0.f);
      float o[9] = {};
#pragma unroll
      for (int d = 0; d < 8; ++d)
#pragma unroll
        for (int e = 0; e < 9; ++e) o[e] = fmaf(qd[d], kvf[d * 9 + e], o[e]);
      float rinv = 1.0f / (o[8] + 1e-15f);
#pragma unroll
      for (int e = 0; e < 8; ++e) res[e][p] = (short)f2bs(o[e] * rinv);
    }
#pragma unroll
    for (int e = 0; e < 8; ++e)
      *(s4v*)(obase + (size_t)e * HW + n0) = res[e];
  }
}

// ---------------------------------------------------------------------------
extern "C" void kernel_launch(void* const* d_in, const int* in_sizes, int n_in,
                              void* d_out, int out_size, void* d_ws, size_t ws_size,
                              hipStream_t stream) {
  const float* x = (const float*)d_in[0];       // [8,256,64,64]
  const float* w_qkv = (const float*)d_in[1];   // [768,256]
  const float* w_dw = (const float*)d_in[2];    // [768,1,5,5]
  const float* w_pw = (const float*)d_in[3];    // [96,8,8]
  const float* w_proj = (const float*)d_in[4];  // [256,512]
  const float* bng = (const float*)d_in[5];
  const float* bnb = (const float*)d_in[6];
  const float* bnm = (const float*)d_in[7];
  const float* bnv = (const float*)d_in[8];
  float* out = (float*)d_out;  // [8,256,64,64]

  // Workspace: 128 MiB, aliased by liveness.
  bf16* qkv = (bf16*)d_ws;                       // [8][768][HW]  48 MiB
  bf16* pw = qkv + (size_t)8 * 768 * HW;         // [8][768][HW]  48 MiB
  bf16* att = pw + (size_t)8 * 768 * HW;         // [8][512][HW]  32 MiB

  // Pre-GEMM1 temporaries (dead regions):
  _Float16* xt_hi = (_Float16*)att;              // [8][HW][256] (att dead until attn)
  // xt_lo plane implicitly at xt_hi + 8*HW*256 (fills att region exactly)
  _Float16* xt_lo = xt_hi + (size_t)8 * HW * 256;
  _Float16* wq_hi = (_Float16*)pw;               // [768][256] x2 planes (pw dead until dwpw)
  _Float16* wq_lo = wq_hi + (size_t)768 * 256;
  // Post-attn temporaries:
  _Float16* wp_hi = (_Float16*)qkv;              // [256][512] x2 planes (qkv dead after attn)
  _Float16* wp_lo = wp_hi + (size_t)256 * 512;
  _Float16* att_t = (_Float16*)pw;               // [8][HW][512] (pw dead after attn)

  // 0) split-convert w_qkv; transpose+split x
  cvt_split_kernel<<<dim3(192), 256, 0, stream>>>(w_qkv, wq_hi, wq_lo, 768 * 256 / 4);
  transpose_split_kernel<<<dim3(64, 4, 8), 256, 0, stream>>>(x, xt_hi, xt_lo);

  // 1) qkv = w_qkv @ x   (M=768, K=256) — split-fp16 MFMA (AP=2, BP=2)
  mfma_gemm_f16<768, 256, 128, 2, 2, false, bf16><<<dim3(32, 6, 8), 256, 0, stream>>>(
      wq_hi, xt_hi, qkv, nullptr, nullptr, nullptr, nullptr);

  // 2) pw = grouped_pointwise(depthwise5x5(qkv))   (overwrites wq planes — dead)
  dwpw_kernel<<<dim3(8, 96, 8), 256, 0, stream>>>(qkv, w_dw, w_pw, pw);

  // 3) att = relu_linear_attention(concat(qkv, pw))  (overwrites xt planes — dead)
  attn_kernel<<<dim3(512), 256, 0, stream>>>(qkv, pw, att);

  // 4) split-convert w_proj (into dead qkv); transpose att (into dead pw)
  cvt_split_kernel<<<dim3(128), 256, 0, stream>>>(w_proj, wp_hi, wp_lo, 256 * 512 / 4);
  transpose_b2h_kernel<<<dim3(64, 8, 8), 256, 0, stream>>>(att, att_t);

  // 5) out = BN(w_proj @ att)  (M=256, K=512) — split-A fp16 MFMA (AP=2, BP=1)
  mfma_gemm_f16<256, 512, 64, 2, 1, true, float><<<dim3(32, 4, 8), 256, 0, stream>>>(
      wp_hi, att_t, out, bng, bnb, bnm, bnv);
}

// Round 3
// 279.153 us; speedup vs baseline: 2.1169x; 1.2426x over previous
//
#include <hip/hip_runtime.h>
#include <hip/hip_bf16.h>

typedef __hip_bfloat16 bf16;

#define HW 4096

typedef short s8v __attribute__((ext_vector_type(8)));
typedef short s4v __attribute__((ext_vector_type(4)));
typedef float f32x4 __attribute__((ext_vector_type(4)));
typedef _Float16 h8v __attribute__((ext_vector_type(8)));
typedef _Float16 h4v __attribute__((ext_vector_type(4)));

__device__ __forceinline__ float b2f(bf16 x) { return __bfloat162float(x); }
__device__ __forceinline__ bf16 f2b(float x) { return __float2bfloat16(x); }

__device__ __forceinline__ unsigned short f2bs(float f) {
  bf16 h = __float2bfloat16(f);
  unsigned short s;
  __builtin_memcpy(&s, &h, 2);
  return s;
}
__device__ __forceinline__ float s2f(short s) {
  return __uint_as_float(((unsigned)(unsigned short)s) << 16);
}
__device__ __forceinline__ short h2s(_Float16 h) {
  short s;
  __builtin_memcpy(&s, &h, 2);
  return s;
}

__device__ __forceinline__ void stv(float* p, float v) { *p = v; }
__device__ __forceinline__ void stv(bf16* p, float v) { *p = f2b(v); }

// ---------------------------------------------------------------------------
// fp32 -> (fp16 hi, fp16 lo) split conversion for weights.
// ---------------------------------------------------------------------------
__global__ __launch_bounds__(256) void cvt_split_kernel(
    const float* __restrict__ W, _Float16* __restrict__ Hi,
    _Float16* __restrict__ Lo, int n4) {
  int i = blockIdx.x * 256 + threadIdx.x;
  if (i >= n4) return;
  f32x4 v = *(const f32x4*)(W + (size_t)i * 4);
  h4v h, l;
#pragma unroll
  for (int q = 0; q < 4; ++q) {
    _Float16 hi = (_Float16)v[q];
    h[q] = hi;
    l[q] = (_Float16)(v[q] - (float)hi);
  }
  *(h4v*)(Hi + (size_t)i * 4) = h;
  *(h4v*)(Lo + (size_t)i * 4) = l;
}

// ---------------------------------------------------------------------------
// Transpose + split: x [b][256][HW] f32 -> hi/lo [b][HW][256] f16.
// ---------------------------------------------------------------------------
__global__ __launch_bounds__(256) void transpose_split_kernel(
    const float* __restrict__ In, _Float16* __restrict__ Hi,
    _Float16* __restrict__ Lo) {
  __shared__ _Float16 sH[64][68];
  __shared__ _Float16 sL[64][68];
  const int b = blockIdx.z;
  const int n0 = blockIdx.x * 64, c0 = blockIdx.y * 64;
  const int tl = threadIdx.x & 15, tr = threadIdx.x >> 4;
  const float* Ib = In + ((size_t)b * 256 + c0) * HW + n0;
#pragma unroll
  for (int i = 0; i < 4; ++i) {
    int cc = tr + i * 16;
    f32x4 v = *(const f32x4*)(Ib + (size_t)cc * HW + tl * 4);
#pragma unroll
    for (int q = 0; q < 4; ++q) {
      _Float16 hi = (_Float16)v[q];
      sH[cc][tl * 4 + q] = hi;
      sL[cc][tl * 4 + q] = (_Float16)(v[q] - (float)hi);
    }
  }
  __syncthreads();
  size_t obase = ((size_t)b * HW + n0) * 256 + c0;
#pragma unroll
  for (int i = 0; i < 4; ++i) {
    int nn = tr + i * 16;
    h4v h, l;
#pragma unroll
    for (int q = 0; q < 4; ++q) {
      h[q] = sH[tl * 4 + q][nn];
      l[q] = sL[tl * 4 + q][nn];
    }
    *(h4v*)(Hi + obase + (size_t)nn * 256 + tl * 4) = h;
    *(h4v*)(Lo + obase + (size_t)nn * 256 + tl * 4) = l;
  }
}

// ---------------------------------------------------------------------------
// Transpose att [b][512][HW] bf16 -> att_t [b][HW][512] f16 (exact convert).
// ---------------------------------------------------------------------------
__global__ __launch_bounds__(256) void transpose_b2h_kernel(
    const bf16* __restrict__ In, _Float16* __restrict__ Outp) {
  __shared__ short sT[64][68];
  const int b = blockIdx.z;
  const int n0 = blockIdx.x * 64, c0 = blockIdx.y * 64;
  const int tl = threadIdx.x & 15, tr = threadIdx.x >> 4;
  const bf16* Ib = In + ((size_t)b * 512 + c0) * HW + n0;
#pragma unroll
  for (int i = 0; i < 4; ++i) {
    int cc = tr + i * 16;
    s4v v = *(const s4v*)(Ib + (size_t)cc * HW + tl * 4);
#pragma unroll
    for (int q = 0; q < 4; ++q) sT[cc][tl * 4 + q] = h2s((_Float16)s2f(v[q]));
  }
  __syncthreads();
  short* Ob = (short*)Outp + ((size_t)b * HW + n0) * 512 + c0;
#pragma unroll
  for (int i = 0; i < 4; ++i) {
    int nn = tr + i * 16;
    s4v r;
#pragma unroll
    for (int q = 0; q < 4; ++q) r[q] = sT[tl * 4 + q][nn];
    *(s4v*)(Ob + (size_t)nn * 512 + tl * 4) = r;
  }
}

// ---------------------------------------------------------------------------
// fp16 MFMA GEMM with split-precision planes. (unchanged from round 2)
// ---------------------------------------------------------------------------
template <int M, int K, int BM, int AP, int BP, bool FUSE_BN, typename TOUT>
__global__ __launch_bounds__(256) void mfma_gemm_f16(
    const _Float16* __restrict__ A,   // [AP][M][K] planes
    const _Float16* __restrict__ Bt,  // [BP][8][HW][K] planes
    TOUT* __restrict__ Out,           // [8][M][HW]
    const float* __restrict__ bng, const float* __restrict__ bnb,
    const float* __restrict__ bnm, const float* __restrict__ bnv) {
  constexpr int WMF = BM / 32;
  constexpr int LDR = 40;
  __shared__ _Float16 sA[AP][BM * LDR];
  __shared__ _Float16 sB[BP][128 * LDR];
  const int b = blockIdx.z;
  const int ob = blockIdx.y * BM;
  const int nb = blockIdx.x * 128;
  const int tid = threadIdx.x;
  const int lane = tid & 63;
  const int wave = tid >> 6;
  const int wm = (wave >> 1) * (BM / 2);
  const int wn = (wave & 1) * 64;
  const int lr = lane & 15;
  const int kg = lane >> 4;

  f32x4 acc[WMF][4] = {};

  for (int k0 = 0; k0 < K; k0 += 32) {
#pragma unroll
    for (int p = 0; p < AP; ++p) {
      const _Float16* Ab = A + (size_t)p * M * K + (size_t)ob * K;
#pragma unroll
      for (int t = 0; t < BM / 64; ++t) {
        int c = t * 256 + tid;
        int row = c >> 2, col = c & 3;
        h8v v = *(const h8v*)(Ab + (size_t)row * K + k0 + col * 8);
        *(h8v*)(&sA[p][row * LDR + col * 8]) = v;
      }
    }
#pragma unroll
    for (int q = 0; q < BP; ++q) {
      const _Float16* Bb =
          Bt + (size_t)q * 8 * HW * K + ((size_t)b * HW + nb) * K;
#pragma unroll
      for (int t = 0; t < 2; ++t) {
        int c = t * 256 + tid;
        int row = c >> 2, col = c & 3;
        h8v v = *(const h8v*)(Bb + (size_t)row * K + k0 + col * 8);
        *(h8v*)(&sB[q][row * LDR + col * 8]) = v;
      }
    }
    __syncthreads();

    h8v af[AP][WMF], bf_[BP][4];
#pragma unroll
    for (int p = 0; p < AP; ++p)
#pragma unroll
      for (int i = 0; i < WMF; ++i)
        af[p][i] = *(const h8v*)(&sA[p][(wm + i * 16 + lr) * LDR + kg * 8]);
#pragma unroll
    for (int q = 0; q < BP; ++q)
#pragma unroll
      for (int j = 0; j < 4; ++j)
        bf_[q][j] = *(const h8v*)(&sB[q][(wn + j * 16 + lr) * LDR + kg * 8]);

#pragma unroll
    for (int i = 0; i < WMF; ++i)
#pragma unroll
      for (int j = 0; j < 4; ++j) {
        acc[i][j] = __builtin_amdgcn_mfma_f32_16x16x32_f16(af[0][i], bf_[0][j],
                                                           acc[i][j], 0, 0, 0);
        if (AP > 1)
          acc[i][j] = __builtin_amdgcn_mfma_f32_16x16x32_f16(
              af[1][i], bf_[0][j], acc[i][j], 0, 0, 0);
        if (BP > 1)
          acc[i][j] = __builtin_amdgcn_mfma_f32_16x16x32_f16(
              af[0][i], bf_[1][j], acc[i][j], 0, 0, 0);
      }
    __syncthreads();
  }

#pragma unroll
  for (int i = 0; i < WMF; ++i) {
#pragma unroll
    for (int r = 0; r < 4; ++r) {
      int o = ob + wm + i * 16 + kg * 4 + r;
      float scale = 1.f, shift = 0.f;
      if (FUSE_BN) {
        scale = bng[o] * rsqrtf(bnv[o] + 1e-5f);
        shift = bnb[o] - bnm[o] * scale;
      }
      TOUT* orow = Out + ((size_t)b * M + o) * HW + nb + wn + lr;
#pragma unroll
      for (int j = 0; j < 4; ++j) {
        float v = acc[i][j][r];
        if (FUSE_BN) v = v * scale + shift;
        stv(orow + j * 16, v);
      }
    }
  }
}

// ---------------------------------------------------------------------------
// Fused depthwise 5x5 conv + grouped pointwise (8->8 per group) — REWRITTEN.
// Block = (b, g, 16-row h-tile). 256 threads: r = tid>>4 (0..15 output rows),
// cg = tid&15 (4-px column group). LDS tile: float sT[8][20][72], image col c
// stored at index c+2 so every 5-tap window read is two aligned ds_read_b128.
// Staging: s8v 16-B global loads, shift-only slot decode. Weights: wave-
// uniform global loads (-> s_load/SGPR), LDS pipe reserved for window reads.
// ---------------------------------------------------------------------------
__global__ __launch_bounds__(256) void dwpw_kernel(
    const bf16* __restrict__ qkv,   // [B, 768, HW]
    const float* __restrict__ wdw,  // [768, 25]
    const float* __restrict__ wpw,  // [96, 8, 8]
    bf16* __restrict__ pw) {        // [B, 768, HW]
  __shared__ float sT[8][20][72];
  const int b = blockIdx.z;
  const int g = blockIdx.y;
  const int h0 = blockIdx.x * 16;
  const int tid = threadIdx.x;
  const bf16* qb = qkv + ((size_t)b * 768 + g * 8) * HW;

  // zero halo columns (LDS idx 0,1,66,67) for all 160 (ci,row) pairs
  if (tid < 160) {
    int ci = tid / 20, rr = tid % 20;
    sT[ci][rr][0] = 0.f;
    sT[ci][rr][1] = 0.f;
    sT[ci][rr][66] = 0.f;
    sT[ci][rr][67] = 0.f;
  }

  // stage: 1280 slots of 8 px; slot -> ci = slot&7, seg = (slot>>3)&7, rr = slot>>6
#pragma unroll
  for (int i = 0; i < 5; ++i) {
    int slot = tid + i * 256;
    int ci = slot & 7;
    int seg = (slot >> 3) & 7;
    int rr = slot >> 6;
    int h = h0 + rr - 2;
    float f[8];
    if (h >= 0 && h < 64) {
      s8v raw = *(const s8v*)(qb + (size_t)ci * HW + h * 64 + seg * 8);
#pragma unroll
      for (int q = 0; q < 8; ++q) f[q] = s2f(raw[q]);
    } else {
#pragma unroll
      for (int q = 0; q < 8; ++q) f[q] = 0.f;
    }
    float* dst = &sT[ci][rr][2 + seg * 8];  // 8-B aligned
#pragma unroll
    for (int q = 0; q < 4; ++q)
      *(float2*)(dst + q * 2) = make_float2(f[q * 2], f[q * 2 + 1]);
  }
  __syncthreads();

  const int r = tid >> 4;        // output row within tile
  const int c4 = (tid & 15) * 4; // output column group (4 px)

  float accdw[8][4] = {};
#pragma unroll
  for (int ci = 0; ci < 8; ++ci) {
#pragma unroll
    for (int dy = 0; dy < 5; ++dy) {
      // window: image cols c4-2 .. c4+5  ==  LDS idx c4 .. c4+7 (two aligned b128)
      f32x4 w0 = *(const f32x4*)(&sT[ci][r + dy][c4]);
      f32x4 w1 = *(const f32x4*)(&sT[ci][r + dy][c4 + 4]);
      float win[8] = {w0[0], w0[1], w0[2], w0[3], w1[0], w1[1], w1[2], w1[3]};
#pragma unroll
      for (int dx = 0; dx < 5; ++dx) {
        float wv = wdw[(g * 8 + ci) * 25 + dy * 5 + dx];  // uniform -> SGPR
#pragma unroll
        for (int j = 0; j < 4; ++j)
          accdw[ci][j] = fmaf(wv, win[j + dx], accdw[ci][j]);
      }
    }
  }

  // grouped pointwise: out[o] = sum_i wpw[g][o][i] * dw[i]; packed bf16 store
  bf16* obase = pw + ((size_t)b * 768 + g * 8) * HW + (h0 + r) * 64 + c4;
#pragma unroll
  for (int o = 0; o < 8; ++o) {
    float a[4] = {};
#pragma unroll
    for (int i = 0; i < 8; ++i) {
      float wv = wpw[g * 64 + o * 8 + i];  // uniform -> SGPR
#pragma unroll
      for (int j = 0; j < 4; ++j) a[j] = fmaf(wv, accdw[i][j], a[j]);
    }
    s4v res;
#pragma unroll
    for (int j = 0; j < 4; ++j) res[j] = (short)f2bs(a[j]);
    *(s4v*)(obase + (size_t)o * HW) = res;
  }
}

// ---------------------------------------------------------------------------
// ReLU linear attention, short4-vectorized loads/stores. (unchanged)
// ---------------------------------------------------------------------------
__global__ __launch_bounds__(256) void attn_kernel(
    const bf16* __restrict__ qkv,  // [B, 768, HW]
    const bf16* __restrict__ pw,   // [B, 768, HW]
    bf16* __restrict__ att) {      // [B, 512, HW]
  const int bh = blockIdx.x;
  const int b = bh >> 6, h = bh & 63;
  const bf16* src = (h < 32) ? qkv + ((size_t)b * 768 + 24 * h) * HW
                             : pw + ((size_t)b * 768 + 24 * h - 768) * HW;
  const int tid = threadIdx.x;
  float kv[72] = {};  // kv[d*9+e]
  for (int n0 = tid * 4; n0 < HW; n0 += 1024) {
    s4v kvec[8], vvec[8];
#pragma unroll
    for (int d = 0; d < 8; ++d)
      kvec[d] = *(const s4v*)(src + (size_t)(8 + d) * HW + n0);
#pragma unroll
    for (int e = 0; e < 8; ++e)
      vvec[e] = *(const s4v*)(src + (size_t)(16 + e) * HW + n0);
#pragma unroll
    for (int p = 0; p < 4; ++p) {
      float kd[8], ve[8];
#pragma unroll
      for (int d = 0; d < 8; ++d) kd[d] = fmaxf(s2f(kvec[d][p]), 0.f);
#pragma unroll
      for (int e = 0; e < 8; ++e) ve[e] = s2f(vvec[e][p]);
#pragma unroll
      for (int d = 0; d < 8; ++d) {
#pragma unroll
        for (int e = 0; e < 8; ++e) kv[d * 9 + e] = fmaf(kd[d], ve[e], kv[d * 9 + e]);
        kv[d * 9 + 8] += kd[d];
      }
    }
  }
  __shared__ float sRed[4][72];
  __shared__ float sKV[72];
  const int lane = tid & 63, wave = tid >> 6;
#pragma unroll
  for (int t = 0; t < 72; ++t) {
    float v = kv[t];
    v += __shfl_down(v, 32);
    v += __shfl_down(v, 16);
    v += __shfl_down(v, 8);
    v += __shfl_down(v, 4);
    v += __shfl_down(v, 2);
    v += __shfl_down(v, 1);
    if (lane == 0) sRed[wave][t] = v;
  }
  __syncthreads();
  if (tid < 72) sKV[tid] = sRed[0][tid] + sRed[1][tid] + sRed[2][tid] + sRed[3][tid];
  __syncthreads();
  float kvf[72];
#pragma unroll
  for (int t = 0; t < 72; ++t) kvf[t] = sKV[t];
  bf16* obase = att + ((size_t)b * 512 + h * 8) * HW;
  for (int n0 = tid * 4; n0 < HW; n0 += 1024) {
    s4v qvec[8];
#pragma unroll
    for (int d = 0; d < 8; ++d)
      qvec[d] = *(const s4v*)(src + (size_t)d * HW + n0);
    s4v res[8];
#pragma unroll
    for (int p = 0; p < 4; ++p) {
      float qd[8];
#pragma unroll
      for (int d = 0; d < 8; ++d) qd[d] = fmaxf(s2f(qvec[d][p]), 0.f);
      float o[9] = {};
#pragma unroll
      for (int d = 0; d < 8; ++d)
#pragma unroll
        for (int e = 0; e < 9; ++e) o[e] = fmaf(qd[d], kvf[d * 9 + e], o[e]);
      float rinv = 1.0f / (o[8] + 1e-15f);
#pragma unroll
      for (int e = 0; e < 8; ++e) res[e][p] = (short)f2bs(o[e] * rinv);
    }
#pragma unroll
    for (int e = 0; e < 8; ++e)
      *(s4v*)(obase + (size_t)e * HW + n0) = res[e];
  }
}

// ---------------------------------------------------------------------------
extern "C" void kernel_launch(void* const* d_in, const int* in_sizes, int n_in,
                              void* d_out, int out_size, void* d_ws, size_t ws_size,
                              hipStream_t stream) {
  const float* x = (const float*)d_in[0];       // [8,256,64,64]
  const float* w_qkv = (const float*)d_in[1];   // [768,256]
  const float* w_dw = (const float*)d_in[2];    // [768,1,5,5]
  const float* w_pw = (const float*)d_in[3];    // [96,8,8]
  const float* w_proj = (const float*)d_in[4];  // [256,512]
  const float* bng = (const float*)d_in[5];
  const float* bnb = (const float*)d_in[6];
  const float* bnm = (const float*)d_in[7];
  const float* bnv = (const float*)d_in[8];
  float* out = (float*)d_out;  // [8,256,64,64]

  // Workspace: 128 MiB, aliased by liveness.
  bf16* qkv = (bf16*)d_ws;                       // [8][768][HW]  48 MiB
  bf16* pw = qkv + (size_t)8 * 768 * HW;         // [8][768][HW]  48 MiB
  bf16* att = pw + (size_t)8 * 768 * HW;         // [8][512][HW]  32 MiB

  _Float16* xt_hi = (_Float16*)att;              // [8][HW][256] (att dead until attn)
  _Float16* xt_lo = xt_hi + (size_t)8 * HW * 256;
  _Float16* wq_hi = (_Float16*)pw;               // [768][256] x2 (pw dead until dwpw)
  _Float16* wq_lo = wq_hi + (size_t)768 * 256;
  _Float16* wp_hi = (_Float16*)qkv;              // [256][512] x2 (qkv dead after attn)
  _Float16* wp_lo = wp_hi + (size_t)256 * 512;
  _Float16* att_t = (_Float16*)pw;               // [8][HW][512] (pw dead after attn)

  // 0) split-convert w_qkv; transpose+split x
  cvt_split_kernel<<<dim3(192), 256, 0, stream>>>(w_qkv, wq_hi, wq_lo, 768 * 256 / 4);
  transpose_split_kernel<<<dim3(64, 4, 8), 256, 0, stream>>>(x, xt_hi, xt_lo);

  // 1) qkv = w_qkv @ x   (M=768, K=256) — split-fp16 MFMA (AP=2, BP=2)
  mfma_gemm_f16<768, 256, 128, 2, 2, false, bf16><<<dim3(32, 6, 8), 256, 0, stream>>>(
      wq_hi, xt_hi, qkv, nullptr, nullptr, nullptr, nullptr);

  // 2) pw = grouped_pointwise(depthwise5x5(qkv))   (overwrites wq planes — dead)
  dwpw_kernel<<<dim3(4, 96, 8), 256, 0, stream>>>(qkv, w_dw, w_pw, pw);

  // 3) att = relu_linear_attention(concat(qkv, pw))  (overwrites xt planes — dead)
  attn_kernel<<<dim3(512), 256, 0, stream>>>(qkv, pw, att);

  // 4) split-convert w_proj (into dead qkv); transpose att (into dead pw)
  cvt_split_kernel<<<dim3(128), 256, 0, stream>>>(w_proj, wp_hi, wp_lo, 256 * 512 / 4);
  transpose_b2h_kernel<<<dim3(64, 8, 8), 256, 0, stream>>>(att, att_t);

  // 5) out = BN(w_proj @ att)  (M=256, K=512) — split-A fp16 MFMA (AP=2, BP=1)
  mfma_gemm_f16<256, 512, 64, 2, 1, true, float><<<dim3(32, 4, 8), 256, 0, stream>>>(
      wp_hi, att_t, out, bng, bnb, bnm, bnv);
}

// Round 4
// 247.111 us; speedup vs baseline: 2.3914x; 1.1297x over previous
//
#include <hip/hip_runtime.h>
#include <hip/hip_bf16.h>

typedef __hip_bfloat16 bf16;

#define HW 4096

typedef short s8v __attribute__((ext_vector_type(8)));
typedef short s4v __attribute__((ext_vector_type(4)));
typedef float f32x4 __attribute__((ext_vector_type(4)));
typedef _Float16 h8v __attribute__((ext_vector_type(8)));
typedef _Float16 h4v __attribute__((ext_vector_type(4)));

typedef __attribute__((address_space(3))) void lds_void;
typedef const __attribute__((address_space(1))) void g_void;

__device__ __forceinline__ float b2f(bf16 x) { return __bfloat162float(x); }
__device__ __forceinline__ bf16 f2b(float x) { return __float2bfloat16(x); }

__device__ __forceinline__ unsigned short f2bs(float f) {
  bf16 h = __float2bfloat16(f);
  unsigned short s;
  __builtin_memcpy(&s, &h, 2);
  return s;
}
__device__ __forceinline__ float s2f(short s) {
  return __uint_as_float(((unsigned)(unsigned short)s) << 16);
}
__device__ __forceinline__ short h2s(_Float16 h) {
  short s;
  __builtin_memcpy(&s, &h, 2);
  return s;
}

__device__ __forceinline__ void stv(float* p, float v) { *p = v; }
__device__ __forceinline__ void stv(bf16* p, float v) { *p = f2b(v); }

// ---------------------------------------------------------------------------
// fp32 -> (fp16 hi, fp16 lo) split conversion for w_qkv.
// ---------------------------------------------------------------------------
__global__ __launch_bounds__(256) void cvt_split_kernel(
    const float* __restrict__ W, _Float16* __restrict__ Hi,
    _Float16* __restrict__ Lo, int n4) {
  int i = blockIdx.x * 256 + threadIdx.x;
  if (i >= n4) return;
  f32x4 v = *(const f32x4*)(W + (size_t)i * 4);
  h4v h, l;
#pragma unroll
  for (int q = 0; q < 4; ++q) {
    _Float16 hi = (_Float16)v[q];
    h[q] = hi;
    l[q] = (_Float16)(v[q] - (float)hi);
  }
  *(h4v*)(Hi + (size_t)i * 4) = h;
  *(h4v*)(Lo + (size_t)i * 4) = l;
}

// ---------------------------------------------------------------------------
// fp32 -> fp16 plain conversion for w_proj (last linear op: bounded error).
// ---------------------------------------------------------------------------
__global__ __launch_bounds__(256) void cvt_f16_kernel(
    const float* __restrict__ W, _Float16* __restrict__ Hi, int n4) {
  int i = blockIdx.x * 256 + threadIdx.x;
  if (i >= n4) return;
  f32x4 v = *(const f32x4*)(W + (size_t)i * 4);
  h4v h;
#pragma unroll
  for (int q = 0; q < 4; ++q) h[q] = (_Float16)v[q];
  *(h4v*)(Hi + (size_t)i * 4) = h;
}

// ---------------------------------------------------------------------------
// Transpose + split: x [b][256][HW] f32 -> hi/lo [b][HW][256] f16.
// ---------------------------------------------------------------------------
__global__ __launch_bounds__(256) void transpose_split_kernel(
    const float* __restrict__ In, _Float16* __restrict__ Hi,
    _Float16* __restrict__ Lo) {
  __shared__ _Float16 sH[64][68];
  __shared__ _Float16 sL[64][68];
  const int b = blockIdx.z;
  const int n0 = blockIdx.x * 64, c0 = blockIdx.y * 64;
  const int tl = threadIdx.x & 15, tr = threadIdx.x >> 4;
  const float* Ib = In + ((size_t)b * 256 + c0) * HW + n0;
#pragma unroll
  for (int i = 0; i < 4; ++i) {
    int cc = tr + i * 16;
    f32x4 v = *(const f32x4*)(Ib + (size_t)cc * HW + tl * 4);
#pragma unroll
    for (int q = 0; q < 4; ++q) {
      _Float16 hi = (_Float16)v[q];
      sH[cc][tl * 4 + q] = hi;
      sL[cc][tl * 4 + q] = (_Float16)(v[q] - (float)hi);
    }
  }
  __syncthreads();
  size_t obase = ((size_t)b * HW + n0) * 256 + c0;
#pragma unroll
  for (int i = 0; i < 4; ++i) {
    int nn = tr + i * 16;
    h4v h, l;
#pragma unroll
    for (int q = 0; q < 4; ++q) {
      h[q] = sH[tl * 4 + q][nn];
      l[q] = sL[tl * 4 + q][nn];
    }
    *(h4v*)(Hi + obase + (size_t)nn * 256 + tl * 4) = h;
    *(h4v*)(Lo + obase + (size_t)nn * 256 + tl * 4) = l;
  }
}

// ---------------------------------------------------------------------------
// Transpose att [b][512][HW] bf16 -> att_t [b][HW][512] f16 (exact convert).
// ---------------------------------------------------------------------------
__global__ __launch_bounds__(256) void transpose_b2h_kernel(
    const bf16* __restrict__ In, _Float16* __restrict__ Outp) {
  __shared__ short sT[64][68];
  const int b = blockIdx.z;
  const int n0 = blockIdx.x * 64, c0 = blockIdx.y * 64;
  const int tl = threadIdx.x & 15, tr = threadIdx.x >> 4;
  const bf16* Ib = In + ((size_t)b * 512 + c0) * HW + n0;
#pragma unroll
  for (int i = 0; i < 4; ++i) {
    int cc = tr + i * 16;
    s4v v = *(const s4v*)(Ib + (size_t)cc * HW + tl * 4);
#pragma unroll
    for (int q = 0; q < 4; ++q) sT[cc][tl * 4 + q] = h2s((_Float16)s2f(v[q]));
  }
  __syncthreads();
  short* Ob = (short*)Outp + ((size_t)b * HW + n0) * 512 + c0;
#pragma unroll
  for (int i = 0; i < 4; ++i) {
    int nn = tr + i * 16;
    s4v r;
#pragma unroll
    for (int q = 0; q < 4; ++q) r[q] = sT[tl * 4 + q][nn];
    *(s4v*)(Ob + (size_t)nn * 512 + tl * 4) = r;
  }
}

// ---------------------------------------------------------------------------
// fp16 MFMA GEMM with split-precision planes, global_load_lds(16B) staging.
// LDS tiles linear [rows][32]; k-chunk source-swizzled kc = col^((row>>1)&3)
// so ds_read_b128 fragment reads sweep all 32 banks per 8-lane group
// (residual 2-way aliasing is free, m136). LDS dest is wave-linear (rule 21:
// linear dest + inverse-swizzled SOURCE + swizzled READ).
// ---------------------------------------------------------------------------
template <int M, int K, int BM, int AP, int BP, bool FUSE_BN, typename TOUT>
__global__ __launch_bounds__(256) void mfma_gemm_f16(
    const _Float16* __restrict__ A,   // [AP][M][K] planes
    const _Float16* __restrict__ Bt,  // [BP][8][HW][K] planes
    TOUT* __restrict__ Out,           // [8][M][HW]
    const float* __restrict__ bng, const float* __restrict__ bnb,
    const float* __restrict__ bnm, const float* __restrict__ bnv) {
  constexpr int WMF = BM / 32;
  __shared__ __align__(16) _Float16 sA[AP][BM * 32];
  __shared__ __align__(16) _Float16 sB[BP][128 * 32];
  const int b = blockIdx.z;
  const int ob = blockIdx.y * BM;
  const int nb = blockIdx.x * 128;
  const int tid = threadIdx.x;
  const int lane = tid & 63;
  const int wave = tid >> 6;
  const int wm = (wave >> 1) * (BM / 2);
  const int wn = (wave & 1) * 64;
  const int lr = lane & 15;
  const int kg = lane >> 4;

  f32x4 acc[WMF][4] = {};

  for (int k0 = 0; k0 < K; k0 += 32) {
    // ---- stage A planes: BM x 32, DMA direct to LDS, 16B/lane ----
#pragma unroll
    for (int p = 0; p < AP; ++p) {
      const _Float16* Ab = A + (size_t)p * M * K + (size_t)ob * K + k0;
#pragma unroll
      for (int t = 0; t < BM / 64; ++t) {
        int c = t * 256 + tid;
        int row = c >> 2, col = c & 3;
        int kc = col ^ ((row >> 1) & 3);
        __builtin_amdgcn_global_load_lds(
            (g_void*)(Ab + (size_t)row * K + kc * 8),
            (lds_void*)(sA[p] + (size_t)(t * 256 + (tid & ~63)) * 8), 16, 0, 0);
      }
    }
    // ---- stage B planes: 128 x 32 ----
#pragma unroll
    for (int q = 0; q < BP; ++q) {
      const _Float16* Bb =
          Bt + (size_t)q * 8 * HW * K + ((size_t)b * HW + nb) * K + k0;
#pragma unroll
      for (int t = 0; t < 2; ++t) {
        int c = t * 256 + tid;
        int row = c >> 2, col = c & 3;
        int kc = col ^ ((row >> 1) & 3);
        __builtin_amdgcn_global_load_lds(
            (g_void*)(Bb + (size_t)row * K + kc * 8),
            (lds_void*)(sB[q] + (size_t)(t * 256 + (tid & ~63)) * 8), 16, 0, 0);
      }
    }
    __syncthreads();  // drains vmcnt -> LDS visible to all waves

    h8v af[AP][WMF], bf_[BP][4];
#pragma unroll
    for (int p = 0; p < AP; ++p)
#pragma unroll
      for (int i = 0; i < WMF; ++i) {
        int r = wm + i * 16 + lr;
        af[p][i] = *(const h8v*)(sA[p] + (size_t)r * 32 + (kg ^ ((r >> 1) & 3)) * 8);
      }
#pragma unroll
    for (int q = 0; q < BP; ++q)
#pragma unroll
      for (int j = 0; j < 4; ++j) {
        int r = wn + j * 16 + lr;
        bf_[q][j] = *(const h8v*)(sB[q] + (size_t)r * 32 + (kg ^ ((r >> 1) & 3)) * 8);
      }

#pragma unroll
    for (int i = 0; i < WMF; ++i)
#pragma unroll
      for (int j = 0; j < 4; ++j) {
        acc[i][j] = __builtin_amdgcn_mfma_f32_16x16x32_f16(af[0][i], bf_[0][j],
                                                           acc[i][j], 0, 0, 0);
        if (AP > 1)
          acc[i][j] = __builtin_amdgcn_mfma_f32_16x16x32_f16(
              af[1][i], bf_[0][j], acc[i][j], 0, 0, 0);
        if (BP > 1)
          acc[i][j] = __builtin_amdgcn_mfma_f32_16x16x32_f16(
              af[0][i], bf_[1][j], acc[i][j], 0, 0, 0);
      }
    __syncthreads();
  }

  // epilogue: D row = (lane>>4)*4 + reg, col = lane&15  (m89-verified)
#pragma unroll
  for (int i = 0; i < WMF; ++i) {
#pragma unroll
    for (int r = 0; r < 4; ++r) {
      int o = ob + wm + i * 16 + kg * 4 + r;
      float scale = 1.f, shift = 0.f;
      if (FUSE_BN) {
        scale = bng[o] * rsqrtf(bnv[o] + 1e-5f);
        shift = bnb[o] - bnm[o] * scale;
      }
      TOUT* orow = Out + ((size_t)b * M + o) * HW + nb + wn + lr;
#pragma unroll
      for (int j = 0; j < 4; ++j) {
        float v = acc[i][j][r];
        if (FUSE_BN) v = v * scale + shift;
        stv(orow + j * 16, v);
      }
    }
  }
}

// ---------------------------------------------------------------------------
// Fused depthwise 5x5 conv + grouped pointwise (8->8 per group). (unchanged)
// ---------------------------------------------------------------------------
__global__ __launch_bounds__(256) void dwpw_kernel(
    const bf16* __restrict__ qkv,   // [B, 768, HW]
    const float* __restrict__ wdw,  // [768, 25]
    const float* __restrict__ wpw,  // [96, 8, 8]
    bf16* __restrict__ pw) {        // [B, 768, HW]
  __shared__ float sT[8][20][72];
  const int b = blockIdx.z;
  const int g = blockIdx.y;
  const int h0 = blockIdx.x * 16;
  const int tid = threadIdx.x;
  const bf16* qb = qkv + ((size_t)b * 768 + g * 8) * HW;

  if (tid < 160) {
    int ci = tid / 20, rr = tid % 20;
    sT[ci][rr][0] = 0.f;
    sT[ci][rr][1] = 0.f;
    sT[ci][rr][66] = 0.f;
    sT[ci][rr][67] = 0.f;
  }

#pragma unroll
  for (int i = 0; i < 5; ++i) {
    int slot = tid + i * 256;
    int ci = slot & 7;
    int seg = (slot >> 3) & 7;
    int rr = slot >> 6;
    int h = h0 + rr - 2;
    float f[8];
    if (h >= 0 && h < 64) {
      s8v raw = *(const s8v*)(qb + (size_t)ci * HW + h * 64 + seg * 8);
#pragma unroll
      for (int q = 0; q < 8; ++q) f[q] = s2f(raw[q]);
    } else {
#pragma unroll
      for (int q = 0; q < 8; ++q) f[q] = 0.f;
    }
    float* dst = &sT[ci][rr][2 + seg * 8];
#pragma unroll
    for (int q = 0; q < 4; ++q)
      *(float2*)(dst + q * 2) = make_float2(f[q * 2], f[q * 2 + 1]);
  }
  __syncthreads();

  const int r = tid >> 4;
  const int c4 = (tid & 15) * 4;

  float accdw[8][4] = {};
#pragma unroll
  for (int ci = 0; ci < 8; ++ci) {
#pragma unroll
    for (int dy = 0; dy < 5; ++dy) {
      f32x4 w0 = *(const f32x4*)(&sT[ci][r + dy][c4]);
      f32x4 w1 = *(const f32x4*)(&sT[ci][r + dy][c4 + 4]);
      float win[8] = {w0[0], w0[1], w0[2], w0[3], w1[0], w1[1], w1[2], w1[3]};
#pragma unroll
      for (int dx = 0; dx < 5; ++dx) {
        float wv = wdw[(g * 8 + ci) * 25 + dy * 5 + dx];
#pragma unroll
        for (int j = 0; j < 4; ++j)
          accdw[ci][j] = fmaf(wv, win[j + dx], accdw[ci][j]);
      }
    }
  }

  bf16* obase = pw + ((size_t)b * 768 + g * 8) * HW + (h0 + r) * 64 + c4;
#pragma unroll
  for (int o = 0; o < 8; ++o) {
    float a[4] = {};
#pragma unroll
    for (int i = 0; i < 8; ++i) {
      float wv = wpw[g * 64 + o * 8 + i];
#pragma unroll
      for (int j = 0; j < 4; ++j) a[j] = fmaf(wv, accdw[i][j], a[j]);
    }
    s4v res;
#pragma unroll
    for (int j = 0; j < 4; ++j) res[j] = (short)f2bs(a[j]);
    *(s4v*)(obase + (size_t)o * HW) = res;
  }
}

// ---------------------------------------------------------------------------
// ReLU linear attention, short4-vectorized loads/stores. (unchanged)
// ---------------------------------------------------------------------------
__global__ __launch_bounds__(256) void attn_kernel(
    const bf16* __restrict__ qkv,  // [B, 768, HW]
    const bf16* __restrict__ pw,   // [B, 768, HW]
    bf16* __restrict__ att) {      // [B, 512, HW]
  const int bh = blockIdx.x;
  const int b = bh >> 6, h = bh & 63;
  const bf16* src = (h < 32) ? qkv + ((size_t)b * 768 + 24 * h) * HW
                             : pw + ((size_t)b * 768 + 24 * h - 768) * HW;
  const int tid = threadIdx.x;
  float kv[72] = {};  // kv[d*9+e]
  for (int n0 = tid * 4; n0 < HW; n0 += 1024) {
    s4v kvec[8], vvec[8];
#pragma unroll
    for (int d = 0; d < 8; ++d)
      kvec[d] = *(const s4v*)(src + (size_t)(8 + d) * HW + n0);
#pragma unroll
    for (int e = 0; e < 8; ++e)
      vvec[e] = *(const s4v*)(src + (size_t)(16 + e) * HW + n0);
#pragma unroll
    for (int p = 0; p < 4; ++p) {
      float kd[8], ve[8];
#pragma unroll
      for (int d = 0; d < 8; ++d) kd[d] = fmaxf(s2f(kvec[d][p]), 0.f);
#pragma unroll
      for (int e = 0; e < 8; ++e) ve[e] = s2f(vvec[e][p]);
#pragma unroll
      for (int d = 0; d < 8; ++d) {
#pragma unroll
        for (int e = 0; e < 8; ++e) kv[d * 9 + e] = fmaf(kd[d], ve[e], kv[d * 9 + e]);
        kv[d * 9 + 8] += kd[d];
      }
    }
  }
  __shared__ float sRed[4][72];
  __shared__ float sKV[72];
  const int lane = tid & 63, wave = tid >> 6;
#pragma unroll
  for (int t = 0; t < 72; ++t) {
    float v = kv[t];
    v += __shfl_down(v, 32);
    v += __shfl_down(v, 16);
    v += __shfl_down(v, 8);
    v += __shfl_down(v, 4);
    v += __shfl_down(v, 2);
    v += __shfl_down(v, 1);
    if (lane == 0) sRed[wave][t] = v;
  }
  __syncthreads();
  if (tid < 72) sKV[tid] = sRed[0][tid] + sRed[1][tid] + sRed[2][tid] + sRed[3][tid];
  __syncthreads();
  float kvf[72];
#pragma unroll
  for (int t = 0; t < 72; ++t) kvf[t] = sKV[t];
  bf16* obase = att + ((size_t)b * 512 + h * 8) * HW;
  for (int n0 = tid * 4; n0 < HW; n0 += 1024) {
    s4v qvec[8];
#pragma unroll
    for (int d = 0; d < 8; ++d)
      qvec[d] = *(const s4v*)(src + (size_t)d * HW + n0);
    s4v res[8];
#pragma unroll
    for (int p = 0; p < 4; ++p) {
      float qd[8];
#pragma unroll
      for (int d = 0; d < 8; ++d) qd[d] = fmaxf(s2f(qvec[d][p]), 0.f);
      float o[9] = {};
#pragma unroll
      for (int d = 0; d < 8; ++d)
#pragma unroll
        for (int e = 0; e < 9; ++e) o[e] = fmaf(qd[d], kvf[d * 9 + e], o[e]);
      float rinv = 1.0f / (o[8] + 1e-15f);
#pragma unroll
      for (int e = 0; e < 8; ++e) res[e][p] = (short)f2bs(o[e] * rinv);
    }
#pragma unroll
    for (int e = 0; e < 8; ++e)
      *(s4v*)(obase + (size_t)e * HW + n0) = res[e];
  }
}

// ---------------------------------------------------------------------------
extern "C" void kernel_launch(void* const* d_in, const int* in_sizes, int n_in,
                              void* d_out, int out_size, void* d_ws, size_t ws_size,
                              hipStream_t stream) {
  const float* x = (const float*)d_in[0];       // [8,256,64,64]
  const float* w_qkv = (const float*)d_in[1];   // [768,256]
  const float* w_dw = (const float*)d_in[2];    // [768,1,5,5]
  const float* w_pw = (const float*)d_in[3];    // [96,8,8]
  const float* w_proj = (const float*)d_in[4];  // [256,512]
  const float* bng = (const float*)d_in[5];
  const float* bnb = (const float*)d_in[6];
  const float* bnm = (const float*)d_in[7];
  const float* bnv = (const float*)d_in[8];
  float* out = (float*)d_out;  // [8,256,64,64]

  // Workspace: 128 MiB, aliased by liveness.
  bf16* qkv = (bf16*)d_ws;                       // [8][768][HW]  48 MiB
  bf16* pw = qkv + (size_t)8 * 768 * HW;         // [8][768][HW]  48 MiB
  bf16* att = pw + (size_t)8 * 768 * HW;         // [8][512][HW]  32 MiB

  _Float16* xt_hi = (_Float16*)att;              // [8][HW][256] (att dead until attn)
  _Float16* xt_lo = xt_hi + (size_t)8 * HW * 256;
  _Float16* wq_hi = (_Float16*)pw;               // [768][256] x2 (pw dead until dwpw)
  _Float16* wq_lo = wq_hi + (size_t)768 * 256;
  _Float16* wp_hi = (_Float16*)qkv;              // [256][512] (qkv dead after attn)
  _Float16* att_t = (_Float16*)pw;               // [8][HW][512] (pw dead after attn)

  // 0) split-convert w_qkv; transpose+split x
  cvt_split_kernel<<<dim3(192), 256, 0, stream>>>(w_qkv, wq_hi, wq_lo, 768 * 256 / 4);
  transpose_split_kernel<<<dim3(64, 4, 8), 256, 0, stream>>>(x, xt_hi, xt_lo);

  // 1) qkv = w_qkv @ x   (M=768, K=256) — split-fp16 MFMA (AP=2, BP=2; 3 planes,
  //    REQUIRED: relu-boundary sign sensitivity in attention)
  mfma_gemm_f16<768, 256, 128, 2, 2, false, bf16><<<dim3(32, 6, 8), 256, 0, stream>>>(
      wq_hi, xt_hi, qkv, nullptr, nullptr, nullptr, nullptr);

  // 2) pw = grouped_pointwise(depthwise5x5(qkv))   (overwrites wq planes — dead)
  dwpw_kernel<<<dim3(4, 96, 8), 256, 0, stream>>>(qkv, w_dw, w_pw, pw);

  // 3) att = relu_linear_attention(concat(qkv, pw))  (overwrites xt planes — dead)
  attn_kernel<<<dim3(512), 256, 0, stream>>>(qkv, pw, att);

  // 4) fp16-convert w_proj (into dead qkv); transpose att (into dead pw)
  cvt_f16_kernel<<<dim3(128), 256, 0, stream>>>(w_proj, wp_hi, 256 * 512 / 4);
  transpose_b2h_kernel<<<dim3(64, 8, 8), 256, 0, stream>>>(att, att_t);

  // 5) out = BN(w_proj @ att)  (M=256, K=512) — plain fp16 MFMA (AP=1, BP=1;
  //    final linear op, error bounded ~2e-4 absolute)
  mfma_gemm_f16<256, 512, 64, 1, 1, true, float><<<dim3(32, 4, 8), 256, 0, stream>>>(
      wp_hi, att_t, out, bng, bnb, bnm, bnv);
}